// Round 14
// baseline (561.391 us; speedup 1.0000x reference)
//
#include <hip/hip_runtime.h>
#include <cstdint>
#include <cstddef>

#define NN 100000
#define NE 1600000
#define FEAT 140
#define EMB 64
#define HID 128
#define LN_EPS 1e-5f
#define BK_SHIFT 9      // 512 nodes per bucket
#define NBUCK 196       // ceil(100000/512)
#define MAXSEG 20480    // LDS staging entries per bucket (avg 8163, 2.5x margin)

typedef unsigned int uint;
typedef unsigned short ushort;
typedef unsigned char uchar;
using short8 = __attribute__((ext_vector_type(8))) short;
using f32x4  = __attribute__((ext_vector_type(4))) float;
using f32x2  = __attribute__((ext_vector_type(2))) float;

#if defined(__has_builtin)
#if __has_builtin(__builtin_amdgcn_cvt_pk_f32_fp8) && __has_builtin(__builtin_amdgcn_cvt_pk_fp8_f32)
#define HAVE_FP8_CVT 1
#endif
#endif

__device__ __forceinline__ float gelu_exact(float x) {
    return 0.5f * x * (1.0f + erff(x * 0.70710678118654752440f));
}

__device__ __forceinline__ uint f2bf(float f) {
    uint u = __float_as_uint(f);
    uint r = (u + 0x7fff + ((u >> 16) & 1)) >> 16;
    return r;
}

__device__ __forceinline__ float bf2f(ushort u) {
    return __uint_as_float(((uint)u) << 16);
}

__device__ __forceinline__ uint pk2bf(float a, float b) {
    return f2bf(a) | (f2bf(b) << 16);
}

// ---- fp8 e4m3 helpers: HW converts when available, manual fallback (R6-verified) ----
__device__ __forceinline__ uchar f2fp8(float f) {
#ifdef HAVE_FP8_CVT
    return (uchar)(__builtin_amdgcn_cvt_pk_fp8_f32(f, f, 0, false) & 0xff);
#else
    uint u = __float_as_uint(f);
    uint s = (u >> 24) & 0x80u;
    uint t = u & 0x7fffffffu;
    if (t >= 0x43E00000u) return (uchar)(s | 0x7Eu);
    uint lsb = (t >> 20) & 1u;
    t += 0x7FFFFu + lsb;
    uint e = t >> 23;
    if (e < 121u) return (uchar)s;
    return (uchar)(s | ((e - 120u) << 3) | ((t >> 20) & 7u));
#endif
}

__device__ __forceinline__ f32x2 fp8pair(uint u) {
#ifdef HAVE_FP8_CVT
    return __builtin_amdgcn_cvt_pk_f32_fp8((int)u, false);
#else
    uint b0 = u & 0xffu, b1 = (u >> 8) & 0xffu;
    uint e0 = b0 & 0x7fu, e1 = b1 & 0x7fu;
    uint s0 = (b0 & 0x80u) << 24, s1 = (b1 & 0x80u) << 24;
    f32x2 r;
    r[0] = __uint_as_float(e0 ? (s0 | ((e0 + 960u) << 20)) : s0);
    r[1] = __uint_as_float(e1 ? (s1 | ((e1 + 960u) << 20)) : s1);
    return r;
#endif
}

// ================= weight packing into MFMA B-fragment order =================
__global__ __launch_bounds__(256) void pack_weights_kernel(
    const float* __restrict__ W_in, const float* __restrict__ Wl,
    const float* __restrict__ Wr,
    ushort* __restrict__ winp, ushort* __restrict__ wcat)
{
    const int tid = blockIdx.x * 256 + threadIdx.x;
    const int NIN = 7 * 8 * 64;        // 3584
    const int NL  = 8 * 8 * 64;        // 4096
    if (tid < NIN) {
        const int kk = tid >> 9;
        const int c  = (tid >> 6) & 7;
        const int l  = tid & 63;
        const int kbase = kk * 32 + (l >> 4) * 8;
        const int col = c * 16 + (l & 15);
        short8 v;
        #pragma unroll
        for (int j = 0; j < 8; ++j) {
            const int k = kbase + j;
            v[j] = (k < 205) ? (short)f2bf(W_in[k * 128 + col]) : (short)0;
        }
        *(short8*)(winp + (size_t)tid * 8) = v;
    } else if (tid < NIN + 4 * NL) {
        const int t2 = tid - NIN;
        const int layer = t2 >> 12;
        const int r = t2 & (NL - 1);
        const int kk = r >> 9;
        const int c  = (r >> 6) & 7;
        const int l  = r & 63;
        const int kbase = kk * 32 + (l >> 4) * 8;
        const int col = c * 16 + (l & 15);
        short8 v;
        #pragma unroll
        for (int j = 0; j < 8; ++j) {
            const int k = kbase + j;
            const float x = (k < 128)
                ? Wl[(size_t)layer * 16384 + k * 128 + col]
                : Wr[(size_t)layer * 16384 + (k - 128) * 128 + col];
            v[j] = (short)f2bf(x);
        }
        *(short8*)(wcat + (size_t)t2 * 8) = v;
    }
}

// ================= input projection (MFMA): hb/h8 = gelu(LN(concat @ W_in + b_in)) =================
// 32 nodes/block, 128 threads (2 waves): finer barrier scope, better tail balance
__global__ __launch_bounds__(128) void input_proj_mfma(
    const float* __restrict__ nf, const float* __restrict__ topo,
    const float* __restrict__ embed, const int* __restrict__ opcode,
    const ushort* __restrict__ Wp, const float* __restrict__ b_in,
    const float* __restrict__ g0, const float* __restrict__ b0,
    ushort* __restrict__ hb_out, uchar* __restrict__ h8_out)
{
    __shared__ ushort xs[32 * 232];
    const int t = threadIdx.x;
    const int node0 = blockIdx.x * 32;

    for (int idx = t; idx < 32 * 35; idx += 128) {
        const int row = idx / 35, c = idx - row * 35;
        const int node = min(node0 + row, NN - 1);
        const float4 v = ((const float4*)nf)[(size_t)node * 35 + c];
        uint2 pk;
        pk.x = pk2bf(v.x, v.y);
        pk.y = pk2bf(v.z, v.w);
        *(uint2*)&xs[row * 232 + c * 4] = pk;
    }
    for (int idx = t; idx < 32 * 16; idx += 128) {
        const int row = idx >> 4, c = idx & 15;
        const int node = min(node0 + row, NN - 1);
        int op = opcode[node];
        op = min(max(op, 0), 127);
        const float4 v = ((const float4*)embed)[op * 16 + c];
        uint2 pk;
        pk.x = pk2bf(v.x, v.y);
        pk.y = pk2bf(v.z, v.w);
        *(uint2*)&xs[row * 232 + 140 + c * 4] = pk;
    }
    for (int idx = t; idx < 32 * 5; idx += 128) {
        const int row = idx / 5, c5 = idx - row * 5;
        uint2 pk = make_uint2(0u, 0u);
        if (c5 == 0) {
            const int node = min(node0 + row, NN - 1);
            pk.x = f2bf(topo[node]);
        }
        *(uint2*)&xs[row * 232 + 204 + c5 * 4] = pk;
    }
    __syncthreads();

    const int w = t >> 6, l = t & 63;   // w in 0..1
    const int gq = l >> 4, li = l & 15;

    f32x4 acc[8];
    #pragma unroll
    for (int c = 0; c < 8; ++c) acc[c] = (f32x4){0.f, 0.f, 0.f, 0.f};

    const short8* Bp = (const short8*)Wp;
    for (int kk = 0; kk < 7; ++kk) {
        const short8 a = *(const short8*)&xs[(w * 16 + li) * 232 + kk * 32 + gq * 8];
        #pragma unroll
        for (int c = 0; c < 8; ++c) {
            const short8 b = Bp[(kk * 8 + c) * 64 + l];
            acc[c] = __builtin_amdgcn_mfma_f32_16x16x32_bf16(a, b, acc[c], 0, 0, 0);
        }
    }

    float bias[8], gam[8], bet[8];
    #pragma unroll
    for (int c = 0; c < 8; ++c) {
        bias[c] = b_in[c * 16 + li];
        gam[c]  = g0[c * 16 + li];
        bet[c]  = b0[c * 16 + li];
    }
    float s[4] = {0, 0, 0, 0}, q[4] = {0, 0, 0, 0};
    #pragma unroll
    for (int c = 0; c < 8; ++c)
        #pragma unroll
        for (int r = 0; r < 4; ++r) {
            const float u = acc[c][r] + bias[c];
            acc[c][r] = u;
            s[r] += u;
            q[r] += u * u;
        }
    #pragma unroll
    for (int off = 1; off < 16; off <<= 1)
        #pragma unroll
        for (int r = 0; r < 4; ++r) {
            s[r] += __shfl_xor(s[r], off);
            q[r] += __shfl_xor(q[r], off);
        }
    #pragma unroll
    for (int r = 0; r < 4; ++r) {
        const int node = node0 + w * 16 + gq * 4 + r;
        if (node >= NN) continue;
        const float mean = s[r] * (1.0f / HID);
        const float var  = q[r] * (1.0f / HID) - mean * mean;
        const float rstd = rsqrtf(var + LN_EPS);
        #pragma unroll
        for (int c = 0; c < 8; ++c) {
            const float y = gelu_exact((acc[c][r] - mean) * rstd * gam[c] + bet[c]);
            hb_out[(size_t)node * 128 + c * 16 + li] = (ushort)f2bf(y);
            h8_out[(size_t)node * 128 + c * 16 + li] = f2fp8(y);
        }
    }
}

// ================= CSR build (bucketed, no per-node global atomics) =================
__global__ __launch_bounds__(256) void hist_kernel(const int* __restrict__ tgt,
                                                   int* __restrict__ bhist) {
    __shared__ int lh[NBUCK];
    for (int i = threadIdx.x; i < NBUCK; i += 256) lh[i] = 0;
    __syncthreads();
    const int e0 = blockIdx.x * 8192;
    const int eend = min(e0 + 8192, NE);
    for (int e = e0 + threadIdx.x; e < eend; e += 256)
        atomicAdd(&lh[tgt[e] >> BK_SHIFT], 1);
    __syncthreads();
    for (int i = threadIdx.x; i < NBUCK; i += 256)
        if (lh[i]) atomicAdd(&bhist[i], lh[i]);
}

__global__ __launch_bounds__(256) void bucket_scan_kernel(const int* __restrict__ bhist,
                                                          int* __restrict__ bpos,
                                                          int* __restrict__ bcur) {
    __shared__ int s_[256];
    const int t = threadIdx.x;
    int v = (t < NBUCK) ? bhist[t] : 0;
    s_[t] = v;
    __syncthreads();
    for (int off = 1; off < 256; off <<= 1) {
        int u = (t >= off) ? s_[t - off] : 0;
        __syncthreads();
        s_[t] += u;
        __syncthreads();
    }
    if (t < NBUCK) { bpos[t] = s_[t] - v; bcur[t] = s_[t] - v; }
}

__global__ __launch_bounds__(256) void partition_kernel(const int* __restrict__ src,
                                                        const int* __restrict__ tgt,
                                                        int* __restrict__ bcur,
                                                        uint2* __restrict__ pairs) {
    __shared__ int lh[NBUCK];
    __shared__ int gbase[NBUCK];
    for (int i = threadIdx.x; i < NBUCK; i += 256) lh[i] = 0;
    __syncthreads();
    const int e0 = blockIdx.x * 2048;
    const int eend = min(e0 + 2048, NE);
    int myb[8], myr[8], mys[8], myt[8];
    int cnt = 0;
    for (int e = e0 + threadIdx.x; e < eend; e += 256) {
        const int tv = tgt[e];
        const int b = tv >> BK_SHIFT;
        myb[cnt] = b; myt[cnt] = tv; mys[cnt] = src[e];
        myr[cnt] = atomicAdd(&lh[b], 1);
        ++cnt;
    }
    __syncthreads();
    for (int i = threadIdx.x; i < NBUCK; i += 256)
        gbase[i] = lh[i] ? atomicAdd(&bcur[i], lh[i]) : 0;
    __syncthreads();
    for (int i = 0; i < cnt; ++i)
        pairs[gbase[myb[i]] + myr[i]] = make_uint2((uint)myt[i], (uint)mys[i]);
}

__global__ __launch_bounds__(256) void bucket_fill_kernel(const uint2* __restrict__ pairs,
                                                          const int* __restrict__ bpos,
                                                          const int* __restrict__ bhist,
                                                          int* __restrict__ offs,
                                                          float* __restrict__ inv_deg,
                                                          int* __restrict__ csr) {
    __shared__ int cnt[512];
    __shared__ int pref[512];
    __shared__ int ssum[256];
    __shared__ int stage[MAXSEG];
    const int t = threadIdx.x;
    const int b = blockIdx.x;
    const int n0 = b << BK_SHIFT;
    const int nn = min(512, NN - n0);
    const int p0 = bpos[b], pc = bhist[b];

    for (int i = t; i < 512; i += 256) cnt[i] = 0;
    __syncthreads();
    for (int i = t; i < pc; i += 256)
        atomicAdd(&cnt[(int)pairs[p0 + i].x - n0], 1);
    __syncthreads();
    const int a0 = cnt[2 * t], a1 = cnt[2 * t + 1];
    ssum[t] = a0 + a1;
    __syncthreads();
    for (int off = 1; off < 256; off <<= 1) {
        int u = (t >= off) ? ssum[t - off] : 0;
        __syncthreads();
        ssum[t] += u;
        __syncthreads();
    }
    const int ebase = ssum[t] - a0 - a1;
    pref[2 * t] = ebase;
    pref[2 * t + 1] = ebase + a0;
    __syncthreads();
    for (int i = t; i < nn; i += 256) {
        offs[n0 + i] = p0 + pref[i];
        inv_deg[n0 + i] = 1.0f / fmaxf((float)cnt[i], 1.0f);
    }
    if (b == NBUCK - 1 && t == 0) offs[NN] = NE;
    __syncthreads();
    for (int i = t; i < 512; i += 256) cnt[i] = 0;
    __syncthreads();
    if (pc <= MAXSEG) {
        for (int i = t; i < pc; i += 256) {
            const uint2 pr = pairs[p0 + i];
            const int ln = (int)pr.x - n0;
            const int p = atomicAdd(&cnt[ln], 1);
            stage[pref[ln] + p] = (int)pr.y;
        }
        __syncthreads();
        for (int i = t; i < pc; i += 256) csr[p0 + i] = stage[i];
    } else {
        for (int i = t; i < pc; i += 256) {
            const uint2 pr = pairs[p0 + i];
            const int ln = (int)pr.x - n0;
            const int p = atomicAdd(&cnt[ln], 1);
            csr[p0 + pref[ln] + p] = (int)pr.y;
        }
    }
}

// ================= gather: aggb[n] = bf16( inv_deg[n] * sum h8[src] ) =================
// XCD-aligned swizzle (R12); aggb stored nontemporal: full-line coalesced writes,
// skip the write-allocate RFO fill (the ~25 MB of gather FETCH above compulsory)
__global__ __launch_bounds__(256) void gather_kernel(const uchar* __restrict__ h8,
                                                     const int* __restrict__ csr,
                                                     const int* __restrict__ offs,
                                                     const float* __restrict__ inv_deg,
                                                     ushort* __restrict__ aggb) {
    const int x = blockIdx.x & 7;          // assumed XCD (round-robin dispatch)
    const int j = blockIdx.x >> 3;         // [0, 3136)
    const int n0 = (x + 8 * (j >> 4)) * 16 + (j & 15);
    if (n0 >= NN / 4) return;
    const int node = n0 * 4 + (threadIdx.x >> 6);
    const int lane = threadIdx.x & 63;
    if (node >= NN) return;
    const int beg = offs[node];
    const int end = offs[node + 1];
    const ushort* hp = (const ushort*)h8;   // 64 ushorts (2 fp8 each) per row
    float ax = 0.0f, ay = 0.0f;
    int j2 = beg;
    for (; j2 + 16 <= end; j2 += 16) {
        int ss[16];
        uint uu[16];
        #pragma unroll
        for (int i = 0; i < 16; ++i) ss[i] = csr[j2 + i];
        #pragma unroll
        for (int i = 0; i < 16; ++i) uu[i] = hp[(size_t)ss[i] * 64 + lane];
        float axp[4], ayp[4];
        #pragma unroll
        for (int p = 0; p < 4; ++p) {
            f32x2 v0 = fp8pair(uu[4 * p + 0]);
            f32x2 v1 = fp8pair(uu[4 * p + 1]);
            f32x2 v2 = fp8pair(uu[4 * p + 2]);
            f32x2 v3 = fp8pair(uu[4 * p + 3]);
            axp[p] = (v0[0] + v1[0]) + (v2[0] + v3[0]);
            ayp[p] = (v0[1] + v1[1]) + (v2[1] + v3[1]);
        }
        ax += (axp[0] + axp[1]) + (axp[2] + axp[3]);
        ay += (ayp[0] + ayp[1]) + (ayp[2] + ayp[3]);
    }
    for (; j2 + 4 <= end; j2 += 4) {
        int ss[4];
        uint uu[4];
        #pragma unroll
        for (int i = 0; i < 4; ++i) ss[i] = csr[j2 + i];
        #pragma unroll
        for (int i = 0; i < 4; ++i) uu[i] = hp[(size_t)ss[i] * 64 + lane];
        f32x2 v0 = fp8pair(uu[0]);
        f32x2 v1 = fp8pair(uu[1]);
        f32x2 v2 = fp8pair(uu[2]);
        f32x2 v3 = fp8pair(uu[3]);
        ax += (v0[0] + v1[0]) + (v2[0] + v3[0]);
        ay += (v0[1] + v1[1]) + (v2[1] + v3[1]);
    }
    for (; j2 < end; ++j2) {
        f32x2 v = fp8pair(hp[(size_t)csr[j2] * 64 + lane]);
        ax += v[0];
        ay += v[1];
    }
    const float id = inv_deg[node];
    const uint lo = f2bf(ax * id);
    const uint hi = f2bf(ay * id);
    __builtin_nontemporal_store(lo | (hi << 16), (uint*)aggb + (size_t)node * 64 + lane);
}

// ================= fused layer (MFMA): hb/h8 = LN(hb + gelu([agg|hb] @ [Wl;Wr] + bl)) =================
__global__ __launch_bounds__(256) void layer_mfma(
    ushort* __restrict__ hb, uchar* __restrict__ h8,
    const ushort* __restrict__ aggb,
    const ushort* __restrict__ Wp, const float* __restrict__ bl,
    const float* __restrict__ g, const float* __restrict__ b,
    float* __restrict__ hout, int write_f32)
{
    const int t = threadIdx.x;
    const int w = t >> 6, l = t & 63;
    const int gq = l >> 4, li = l & 15;
    const int node0 = blockIdx.x * 64;
    const int ar = min(node0 + w * 16 + li, NN - 1);

    f32x4 acc[8];
    #pragma unroll
    for (int c = 0; c < 8; ++c) acc[c] = (f32x4){0.f, 0.f, 0.f, 0.f};

    const short8* Bp = (const short8*)Wp;
    const short8* Ag = (const short8*)aggb;
    const short8* Hg = (const short8*)hb;
    #pragma unroll
    for (int kk = 0; kk < 8; ++kk) {
        const short8 a = (kk < 4) ? Ag[(size_t)ar * 16 + kk * 4 + gq]
                                  : Hg[(size_t)ar * 16 + (kk - 4) * 4 + gq];
        #pragma unroll
        for (int c = 0; c < 8; ++c) {
            const short8 bf = Bp[(kk * 8 + c) * 64 + l];
            acc[c] = __builtin_amdgcn_mfma_f32_16x16x32_bf16(a, bf, acc[c], 0, 0, 0);
        }
    }

    float bias[8], gam[8], bet[8];
    #pragma unroll
    for (int c = 0; c < 8; ++c) {
        bias[c] = bl[c * 16 + li];
        gam[c]  = g[c * 16 + li];
        bet[c]  = b[c * 16 + li];
    }
    float s[4] = {0, 0, 0, 0}, q[4] = {0, 0, 0, 0};
    #pragma unroll
    for (int r = 0; r < 4; ++r) {
        const int nd = min(node0 + w * 16 + gq * 4 + r, NN - 1);
        #pragma unroll
        for (int c = 0; c < 8; ++c) {
            const float hv = bf2f(hb[(size_t)nd * 128 + c * 16 + li]);
            const float tv = hv + gelu_exact(acc[c][r] + bias[c]);
            acc[c][r] = tv;
            s[r] += tv;
            q[r] += tv * tv;
        }
    }
    #pragma unroll
    for (int off = 1; off < 16; off <<= 1)
        #pragma unroll
        for (int r = 0; r < 4; ++r) {
            s[r] += __shfl_xor(s[r], off);
            q[r] += __shfl_xor(q[r], off);
        }
    #pragma unroll
    for (int r = 0; r < 4; ++r) {
        const int node = node0 + w * 16 + gq * 4 + r;
        if (node >= NN) continue;
        const float mean = s[r] * (1.0f / HID);
        const float var  = q[r] * (1.0f / HID) - mean * mean;
        const float rstd = rsqrtf(var + LN_EPS);
        #pragma unroll
        for (int c = 0; c < 8; ++c) {
            const float y = (acc[c][r] - mean) * rstd * gam[c] + bet[c];
            if (write_f32) {
                hout[(size_t)node * 128 + c * 16 + li] = y;
            } else {
                hb[(size_t)node * 128 + c * 16 + li] = (ushort)f2bf(y);
                h8[(size_t)node * 128 + c * 16 + li] = f2fp8(y);
            }
        }
    }
}

extern "C" void kernel_launch(void* const* d_in, const int* in_sizes, int n_in,
                              void* d_out, int out_size, void* d_ws, size_t ws_size,
                              hipStream_t stream) {
    const float* node_feat = (const float*)d_in[0];
    const float* topo      = (const float*)d_in[1];
    const float* embed     = (const float*)d_in[2];
    const float* W_in      = (const float*)d_in[3];
    const float* b_in      = (const float*)d_in[4];
    const float* ln0_g     = (const float*)d_in[5];
    const float* ln0_b     = (const float*)d_in[6];
    const float* Wl        = (const float*)d_in[7];
    const float* bl        = (const float*)d_in[8];
    const float* Wr        = (const float*)d_in[9];
    const float* ln_g      = (const float*)d_in[10];
    const float* ln_b      = (const float*)d_in[11];
    const int*   opcode    = (const int*)d_in[12];
    const int*   edge      = (const int*)d_in[13];
    const int*   e_src = edge;
    const int*   e_tgt = edge + NE;

    float* h = (float*)d_out;   // final output 100000 x 128 f32

    char* w = (char*)d_ws;
    ushort* hb     = (ushort*)w;  w += (size_t)NN * HID * sizeof(ushort);   // 25.6 MB
    ushort* aggb   = (ushort*)w;  w += (size_t)NN * HID * sizeof(ushort);   // 25.6 MB
    float* inv_deg = (float*)w;   w += 400016;
    int*   offs    = (int*)w;     w += 400016;    // NN+1 ints
    int*   bhist   = (int*)w;     w += 1024;
    int*   bpos    = (int*)w;     w += 1024;
    int*   bcur    = (int*)w;     w += 1024;
    int*   csr     = (int*)w;     w += (size_t)NE * sizeof(int);            // 6.4 MB
    // pairs (NE*8 = 12.8 MB) and h8 (NN*128 = 12.8 MB) ALIAS: pairs is consumed
    // by bucket_fill before input_proj writes h8 (same stream, sequential).
    uint2* pairs   = (uint2*)w;
    uchar* h8      = (uchar*)w;   w += (size_t)NE * sizeof(uint2);          // 12.8 MB
    ushort* winp   = (ushort*)w;  w += 7 * 8 * 64 * 8 * sizeof(ushort);     // 57 KB
    ushort* wcat   = (ushort*)w;  w += 4 * 8 * 8 * 64 * 8 * sizeof(ushort); // 262 KB

    pack_weights_kernel<<<78, 256, 0, stream>>>(W_in, Wl, Wr, winp, wcat);

    // CSR build first (pairs buffer), then input_proj overwrites pairs as h8
    hipMemsetAsync(bhist, 0, NBUCK * sizeof(int), stream);
    hist_kernel<<<(NE + 8191) / 8192, 256, 0, stream>>>(e_tgt, bhist);
    bucket_scan_kernel<<<1, 256, 0, stream>>>(bhist, bpos, bcur);
    partition_kernel<<<(NE + 2047) / 2048, 256, 0, stream>>>(e_src, e_tgt, bcur, pairs);
    bucket_fill_kernel<<<NBUCK, 256, 0, stream>>>(pairs, bpos, bhist, offs, inv_deg, csr);

    input_proj_mfma<<<(NN + 31) / 32, 128, 0, stream>>>(
        node_feat, topo, embed, opcode, winp, b_in, ln0_g, ln0_b, hb, h8);

    for (int layer = 0; layer < 4; ++layer) {
        gather_kernel<<<8 * 3136, 256, 0, stream>>>(h8, csr, offs, inv_deg, aggb);
        layer_mfma<<<(NN + 63) / 64, 256, 0, stream>>>(
            hb, h8, aggb, wcat + (size_t)layer * 8 * 8 * 64 * 8,
            bl + (size_t)layer * HID,
            ln_g + (size_t)layer * HID, ln_b + (size_t)layer * HID,
            h, layer == 3 ? 1 : 0);
    }
}

// Round 16
// 546.485 us; speedup vs baseline: 1.0273x; 1.0273x over previous
//
#include <hip/hip_runtime.h>
#include <cstdint>
#include <cstddef>

#define NN 100000
#define NE 1600000
#define FEAT 140
#define EMB 64
#define HID 128
#define LN_EPS 1e-5f
#define BK_SHIFT 9      // 512 nodes per bucket
#define NBUCK 196       // ceil(100000/512)
#define MAXSEG 20480    // LDS staging entries per bucket (avg 8163, 2.5x margin)

typedef unsigned int uint;
typedef unsigned short ushort;
typedef unsigned char uchar;
using short8 = __attribute__((ext_vector_type(8))) short;
using f32x4  = __attribute__((ext_vector_type(4))) float;
using f32x2  = __attribute__((ext_vector_type(2))) float;
using uintx2 = __attribute__((ext_vector_type(2))) uint;   // native vector for nontemporal store

#if defined(__has_builtin)
#if __has_builtin(__builtin_amdgcn_cvt_pk_f32_fp8) && __has_builtin(__builtin_amdgcn_cvt_pk_fp8_f32)
#define HAVE_FP8_CVT 1
#endif
#endif

__device__ __forceinline__ float gelu_exact(float x) {
    return 0.5f * x * (1.0f + erff(x * 0.70710678118654752440f));
}

__device__ __forceinline__ uint f2bf(float f) {
    uint u = __float_as_uint(f);
    uint r = (u + 0x7fff + ((u >> 16) & 1)) >> 16;
    return r;
}

__device__ __forceinline__ float bf2f(ushort u) {
    return __uint_as_float(((uint)u) << 16);
}

__device__ __forceinline__ uint pk2bf(float a, float b) {
    return f2bf(a) | (f2bf(b) << 16);
}

// ---- fp8 e4m3 helpers: HW converts when available, manual fallback (R6-verified) ----
__device__ __forceinline__ uchar f2fp8(float f) {
#ifdef HAVE_FP8_CVT
    return (uchar)(__builtin_amdgcn_cvt_pk_fp8_f32(f, f, 0, false) & 0xff);
#else
    uint u = __float_as_uint(f);
    uint s = (u >> 24) & 0x80u;
    uint t = u & 0x7fffffffu;
    if (t >= 0x43E00000u) return (uchar)(s | 0x7Eu);
    uint lsb = (t >> 20) & 1u;
    t += 0x7FFFFu + lsb;
    uint e = t >> 23;
    if (e < 121u) return (uchar)s;
    return (uchar)(s | ((e - 120u) << 3) | ((t >> 20) & 7u));
#endif
}

__device__ __forceinline__ f32x2 fp8pair(uint u) {   // decodes bytes 0,1
#ifdef HAVE_FP8_CVT
    return __builtin_amdgcn_cvt_pk_f32_fp8((int)u, false);
#else
    uint b0 = u & 0xffu, b1 = (u >> 8) & 0xffu;
    uint e0 = b0 & 0x7fu, e1 = b1 & 0x7fu;
    uint s0 = (b0 & 0x80u) << 24, s1 = (b1 & 0x80u) << 24;
    f32x2 r;
    r[0] = __uint_as_float(e0 ? (s0 | ((e0 + 960u) << 20)) : s0);
    r[1] = __uint_as_float(e1 ? (s1 | ((e1 + 960u) << 20)) : s1);
    return r;
#endif
}

__device__ __forceinline__ f32x2 fp8pair_hi(uint u) {   // decodes bytes 2,3
#ifdef HAVE_FP8_CVT
    return __builtin_amdgcn_cvt_pk_f32_fp8((int)u, true);
#else
    return fp8pair(u >> 16);
#endif
}

// ================= weight packing into MFMA B-fragment order =================
__global__ __launch_bounds__(256) void pack_weights_kernel(
    const float* __restrict__ W_in, const float* __restrict__ Wl,
    const float* __restrict__ Wr,
    ushort* __restrict__ winp, ushort* __restrict__ wcat)
{
    const int tid = blockIdx.x * 256 + threadIdx.x;
    const int NIN = 7 * 8 * 64;        // 3584
    const int NL  = 8 * 8 * 64;        // 4096
    if (tid < NIN) {
        const int kk = tid >> 9;
        const int c  = (tid >> 6) & 7;
        const int l  = tid & 63;
        const int kbase = kk * 32 + (l >> 4) * 8;
        const int col = c * 16 + (l & 15);
        short8 v;
        #pragma unroll
        for (int j = 0; j < 8; ++j) {
            const int k = kbase + j;
            v[j] = (k < 205) ? (short)f2bf(W_in[k * 128 + col]) : (short)0;
        }
        *(short8*)(winp + (size_t)tid * 8) = v;
    } else if (tid < NIN + 4 * NL) {
        const int t2 = tid - NIN;
        const int layer = t2 >> 12;
        const int r = t2 & (NL - 1);
        const int kk = r >> 9;
        const int c  = (r >> 6) & 7;
        const int l  = r & 63;
        const int kbase = kk * 32 + (l >> 4) * 8;
        const int col = c * 16 + (l & 15);
        short8 v;
        #pragma unroll
        for (int j = 0; j < 8; ++j) {
            const int k = kbase + j;
            const float x = (k < 128)
                ? Wl[(size_t)layer * 16384 + k * 128 + col]
                : Wr[(size_t)layer * 16384 + (k - 128) * 128 + col];
            v[j] = (short)f2bf(x);
        }
        *(short8*)(wcat + (size_t)t2 * 8) = v;
    }
}

// ================= input projection (MFMA): hb/h8 = gelu(LN(concat @ W_in + b_in)) =================
__global__ __launch_bounds__(128) void input_proj_mfma(
    const float* __restrict__ nf, const float* __restrict__ topo,
    const float* __restrict__ embed, const int* __restrict__ opcode,
    const ushort* __restrict__ Wp, const float* __restrict__ b_in,
    const float* __restrict__ g0, const float* __restrict__ b0,
    ushort* __restrict__ hb_out, uchar* __restrict__ h8_out)
{
    __shared__ ushort xs[32 * 232];
    const int t = threadIdx.x;
    const int node0 = blockIdx.x * 32;

    for (int idx = t; idx < 32 * 35; idx += 128) {
        const int row = idx / 35, c = idx - row * 35;
        const int node = min(node0 + row, NN - 1);
        const float4 v = ((const float4*)nf)[(size_t)node * 35 + c];
        uint2 pk;
        pk.x = pk2bf(v.x, v.y);
        pk.y = pk2bf(v.z, v.w);
        *(uint2*)&xs[row * 232 + c * 4] = pk;
    }
    for (int idx = t; idx < 32 * 16; idx += 128) {
        const int row = idx >> 4, c = idx & 15;
        const int node = min(node0 + row, NN - 1);
        int op = opcode[node];
        op = min(max(op, 0), 127);
        const float4 v = ((const float4*)embed)[op * 16 + c];
        uint2 pk;
        pk.x = pk2bf(v.x, v.y);
        pk.y = pk2bf(v.z, v.w);
        *(uint2*)&xs[row * 232 + 140 + c * 4] = pk;
    }
    for (int idx = t; idx < 32 * 5; idx += 128) {
        const int row = idx / 5, c5 = idx - row * 5;
        uint2 pk = make_uint2(0u, 0u);
        if (c5 == 0) {
            const int node = min(node0 + row, NN - 1);
            pk.x = f2bf(topo[node]);
        }
        *(uint2*)&xs[row * 232 + 204 + c5 * 4] = pk;
    }
    __syncthreads();

    const int w = t >> 6, l = t & 63;   // w in 0..1
    const int gq = l >> 4, li = l & 15;

    f32x4 acc[8];
    #pragma unroll
    for (int c = 0; c < 8; ++c) acc[c] = (f32x4){0.f, 0.f, 0.f, 0.f};

    const short8* Bp = (const short8*)Wp;
    for (int kk = 0; kk < 7; ++kk) {
        const short8 a = *(const short8*)&xs[(w * 16 + li) * 232 + kk * 32 + gq * 8];
        #pragma unroll
        for (int c = 0; c < 8; ++c) {
            const short8 b = Bp[(kk * 8 + c) * 64 + l];
            acc[c] = __builtin_amdgcn_mfma_f32_16x16x32_bf16(a, b, acc[c], 0, 0, 0);
        }
    }

    float bias[8], gam[8], bet[8];
    #pragma unroll
    for (int c = 0; c < 8; ++c) {
        bias[c] = b_in[c * 16 + li];
        gam[c]  = g0[c * 16 + li];
        bet[c]  = b0[c * 16 + li];
    }
    float s[4] = {0, 0, 0, 0}, q[4] = {0, 0, 0, 0};
    #pragma unroll
    for (int c = 0; c < 8; ++c)
        #pragma unroll
        for (int r = 0; r < 4; ++r) {
            const float u = acc[c][r] + bias[c];
            acc[c][r] = u;
            s[r] += u;
            q[r] += u * u;
        }
    #pragma unroll
    for (int off = 1; off < 16; off <<= 1)
        #pragma unroll
        for (int r = 0; r < 4; ++r) {
            s[r] += __shfl_xor(s[r], off);
            q[r] += __shfl_xor(q[r], off);
        }
    #pragma unroll
    for (int r = 0; r < 4; ++r) {
        const int node = node0 + w * 16 + gq * 4 + r;
        if (node >= NN) continue;
        const float mean = s[r] * (1.0f / HID);
        const float var  = q[r] * (1.0f / HID) - mean * mean;
        const float rstd = rsqrtf(var + LN_EPS);
        #pragma unroll
        for (int c = 0; c < 8; ++c) {
            const float y = gelu_exact((acc[c][r] - mean) * rstd * gam[c] + bet[c]);
            hb_out[(size_t)node * 128 + c * 16 + li] = (ushort)f2bf(y);
            h8_out[(size_t)node * 128 + c * 16 + li] = f2fp8(y);
        }
    }
}

// ================= CSR build (bucketed, no per-node global atomics) =================
__global__ __launch_bounds__(256) void hist_kernel(const int* __restrict__ tgt,
                                                   int* __restrict__ bhist) {
    __shared__ int lh[NBUCK];
    for (int i = threadIdx.x; i < NBUCK; i += 256) lh[i] = 0;
    __syncthreads();
    const int e0 = blockIdx.x * 8192;
    const int eend = min(e0 + 8192, NE);
    for (int e = e0 + threadIdx.x; e < eend; e += 256)
        atomicAdd(&lh[tgt[e] >> BK_SHIFT], 1);
    __syncthreads();
    for (int i = threadIdx.x; i < NBUCK; i += 256)
        if (lh[i]) atomicAdd(&bhist[i], lh[i]);
}

__global__ __launch_bounds__(256) void bucket_scan_kernel(const int* __restrict__ bhist,
                                                          int* __restrict__ bpos,
                                                          int* __restrict__ bcur) {
    __shared__ int s_[256];
    const int t = threadIdx.x;
    int v = (t < NBUCK) ? bhist[t] : 0;
    s_[t] = v;
    __syncthreads();
    for (int off = 1; off < 256; off <<= 1) {
        int u = (t >= off) ? s_[t - off] : 0;
        __syncthreads();
        s_[t] += u;
        __syncthreads();
    }
    if (t < NBUCK) { bpos[t] = s_[t] - v; bcur[t] = s_[t] - v; }
}

__global__ __launch_bounds__(256) void partition_kernel(const int* __restrict__ src,
                                                        const int* __restrict__ tgt,
                                                        int* __restrict__ bcur,
                                                        uint2* __restrict__ pairs) {
    __shared__ int lh[NBUCK];
    __shared__ int gbase[NBUCK];
    for (int i = threadIdx.x; i < NBUCK; i += 256) lh[i] = 0;
    __syncthreads();
    const int e0 = blockIdx.x * 2048;
    const int eend = min(e0 + 2048, NE);
    int myb[8], myr[8], mys[8], myt[8];
    int cnt = 0;
    for (int e = e0 + threadIdx.x; e < eend; e += 256) {
        const int tv = tgt[e];
        const int b = tv >> BK_SHIFT;
        myb[cnt] = b; myt[cnt] = tv; mys[cnt] = src[e];
        myr[cnt] = atomicAdd(&lh[b], 1);
        ++cnt;
    }
    __syncthreads();
    for (int i = threadIdx.x; i < NBUCK; i += 256)
        gbase[i] = lh[i] ? atomicAdd(&bcur[i], lh[i]) : 0;
    __syncthreads();
    for (int i = 0; i < cnt; ++i)
        pairs[gbase[myb[i]] + myr[i]] = make_uint2((uint)myt[i], (uint)mys[i]);
}

__global__ __launch_bounds__(256) void bucket_fill_kernel(const uint2* __restrict__ pairs,
                                                          const int* __restrict__ bpos,
                                                          const int* __restrict__ bhist,
                                                          int* __restrict__ offs,
                                                          float* __restrict__ inv_deg,
                                                          int* __restrict__ csr) {
    __shared__ int cnt[512];
    __shared__ int pref[512];
    __shared__ int ssum[256];
    __shared__ int stage[MAXSEG];
    const int t = threadIdx.x;
    const int b = blockIdx.x;
    const int n0 = b << BK_SHIFT;
    const int nn = min(512, NN - n0);
    const int p0 = bpos[b], pc = bhist[b];

    for (int i = t; i < 512; i += 256) cnt[i] = 0;
    __syncthreads();
    for (int i = t; i < pc; i += 256)
        atomicAdd(&cnt[(int)pairs[p0 + i].x - n0], 1);
    __syncthreads();
    const int a0 = cnt[2 * t], a1 = cnt[2 * t + 1];
    ssum[t] = a0 + a1;
    __syncthreads();
    for (int off = 1; off < 256; off <<= 1) {
        int u = (t >= off) ? ssum[t - off] : 0;
        __syncthreads();
        ssum[t] += u;
        __syncthreads();
    }
    const int ebase = ssum[t] - a0 - a1;
    pref[2 * t] = ebase;
    pref[2 * t + 1] = ebase + a0;
    __syncthreads();
    for (int i = t; i < nn; i += 256) {
        offs[n0 + i] = p0 + pref[i];
        inv_deg[n0 + i] = 1.0f / fmaxf((float)cnt[i], 1.0f);
    }
    if (b == NBUCK - 1 && t == 0) offs[NN] = NE;
    __syncthreads();
    for (int i = t; i < 512; i += 256) cnt[i] = 0;
    __syncthreads();
    if (pc <= MAXSEG) {
        for (int i = t; i < pc; i += 256) {
            const uint2 pr = pairs[p0 + i];
            const int ln = (int)pr.x - n0;
            const int p = atomicAdd(&cnt[ln], 1);
            stage[pref[ln] + p] = (int)pr.y;
        }
        __syncthreads();
        for (int i = t; i < pc; i += 256) csr[p0 + i] = stage[i];
    } else {
        for (int i = t; i < pc; i += 256) {
            const uint2 pr = pairs[p0 + i];
            const int ln = (int)pr.x - n0;
            const int p = atomicAdd(&cnt[ln], 1);
            csr[p0 + pref[ln] + p] = (int)pr.y;
        }
    }
}

// ================= gather: aggb[n] = bf16( inv_deg[n] * sum h8[src] ) =================
// 4B/lane, 32 lanes/row: each VMEM instruction fetches TWO edges' rows (2 lines)
// -> half the miss-instructions of the 2B/lane version, same lines in flight.
// half = lane>>5 selects which edge of a pair; final 4x shfl_xor(32) merges.
__global__ __launch_bounds__(256) void gather_kernel(const uchar* __restrict__ h8,
                                                     const int* __restrict__ csr,
                                                     const int* __restrict__ offs,
                                                     const float* __restrict__ inv_deg,
                                                     ushort* __restrict__ aggb) {
    const int x = blockIdx.x & 7;          // XCD-aligned swizzle (R12)
    const int jb = blockIdx.x >> 3;
    const int n0 = (x + 8 * (jb >> 4)) * 16 + (jb & 15);
    if (n0 >= NN / 4) return;
    const int node = n0 * 4 + (threadIdx.x >> 6);
    if (node >= NN) return;
    const int lane = threadIdx.x & 63;
    const int c    = lane & 31;            // uint column within row (32 uints = 128 B)
    const int half = lane >> 5;            // which edge of the pair
    const uint* hp = (const uint*)h8;      // 32 uints per row
    const int beg = offs[node];
    const int end = offs[node + 1];
    float a0 = 0.f, a1 = 0.f, a2 = 0.f, a3 = 0.f;
    int j2 = beg;
    for (; j2 + 16 <= end; j2 += 16) {     // 16 edges via 8 dual-row loads
        int ss[8];
        uint uu[8];
        #pragma unroll
        for (int i = 0; i < 8; ++i) ss[i] = csr[j2 + 2 * i + half];
        #pragma unroll
        for (int i = 0; i < 8; ++i) uu[i] = hp[(size_t)ss[i] * 32 + c];
        #pragma unroll
        for (int i = 0; i < 8; ++i) {
            const f32x2 lo = fp8pair(uu[i]);
            const f32x2 hi = fp8pair_hi(uu[i]);
            a0 += lo[0]; a1 += lo[1]; a2 += hi[0]; a3 += hi[1];
        }
    }
    for (; j2 + 4 <= end; j2 += 4) {       // 4 edges via 2 dual-row loads
        int ss[2];
        uint uu[2];
        #pragma unroll
        for (int i = 0; i < 2; ++i) ss[i] = csr[j2 + 2 * i + half];
        #pragma unroll
        for (int i = 0; i < 2; ++i) uu[i] = hp[(size_t)ss[i] * 32 + c];
        #pragma unroll
        for (int i = 0; i < 2; ++i) {
            const f32x2 lo = fp8pair(uu[i]);
            const f32x2 hi = fp8pair_hi(uu[i]);
            a0 += lo[0]; a1 += lo[1]; a2 += hi[0]; a3 += hi[1];
        }
    }
    for (; j2 + 2 <= end; j2 += 2) {
        const uint u = hp[(size_t)csr[j2 + half] * 32 + c];
        const f32x2 lo = fp8pair(u);
        const f32x2 hi = fp8pair_hi(u);
        a0 += lo[0]; a1 += lo[1]; a2 += hi[0]; a3 += hi[1];
    }
    if (j2 < end && half == 0) {           // odd leftover edge
        const uint u = hp[(size_t)csr[j2] * 32 + c];
        const f32x2 lo = fp8pair(u);
        const f32x2 hi = fp8pair_hi(u);
        a0 += lo[0]; a1 += lo[1]; a2 += hi[0]; a3 += hi[1];
    }
    a0 += __shfl_xor(a0, 32);
    a1 += __shfl_xor(a1, 32);
    a2 += __shfl_xor(a2, 32);
    a3 += __shfl_xor(a3, 32);
    if (half == 0) {
        const float id = inv_deg[node];
        uintx2 o;
        o[0] = pk2bf(a0 * id, a1 * id);    // cols 4c, 4c+1
        o[1] = pk2bf(a2 * id, a3 * id);    // cols 4c+2, 4c+3
        __builtin_nontemporal_store(o, (uintx2*)((uint*)aggb + (size_t)node * 64 + 2 * c));
    }
}

// ================= fused layer (MFMA): hb/h8 = LN(hb + gelu([agg|hb] @ [Wl;Wr] + bl)) =================
__global__ __launch_bounds__(256) void layer_mfma(
    ushort* __restrict__ hb, uchar* __restrict__ h8,
    const ushort* __restrict__ aggb,
    const ushort* __restrict__ Wp, const float* __restrict__ bl,
    const float* __restrict__ g, const float* __restrict__ b,
    float* __restrict__ hout, int write_f32)
{
    const int t = threadIdx.x;
    const int w = t >> 6, l = t & 63;
    const int gq = l >> 4, li = l & 15;
    const int node0 = blockIdx.x * 64;
    const int ar = min(node0 + w * 16 + li, NN - 1);

    f32x4 acc[8];
    #pragma unroll
    for (int c = 0; c < 8; ++c) acc[c] = (f32x4){0.f, 0.f, 0.f, 0.f};

    const short8* Bp = (const short8*)Wp;
    const short8* Ag = (const short8*)aggb;
    const short8* Hg = (const short8*)hb;
    #pragma unroll
    for (int kk = 0; kk < 8; ++kk) {
        const short8 a = (kk < 4) ? Ag[(size_t)ar * 16 + kk * 4 + gq]
                                  : Hg[(size_t)ar * 16 + (kk - 4) * 4 + gq];
        #pragma unroll
        for (int c = 0; c < 8; ++c) {
            const short8 bf = Bp[(kk * 8 + c) * 64 + l];
            acc[c] = __builtin_amdgcn_mfma_f32_16x16x32_bf16(a, bf, acc[c], 0, 0, 0);
        }
    }

    float bias[8], gam[8], bet[8];
    #pragma unroll
    for (int c = 0; c < 8; ++c) {
        bias[c] = bl[c * 16 + li];
        gam[c]  = g[c * 16 + li];
        bet[c]  = b[c * 16 + li];
    }
    float s[4] = {0, 0, 0, 0}, q[4] = {0, 0, 0, 0};
    #pragma unroll
    for (int r = 0; r < 4; ++r) {
        const int nd = min(node0 + w * 16 + gq * 4 + r, NN - 1);
        #pragma unroll
        for (int c = 0; c < 8; ++c) {
            const float hv = bf2f(hb[(size_t)nd * 128 + c * 16 + li]);
            const float tv = hv + gelu_exact(acc[c][r] + bias[c]);
            acc[c][r] = tv;
            s[r] += tv;
            q[r] += tv * tv;
        }
    }
    #pragma unroll
    for (int off = 1; off < 16; off <<= 1)
        #pragma unroll
        for (int r = 0; r < 4; ++r) {
            s[r] += __shfl_xor(s[r], off);
            q[r] += __shfl_xor(q[r], off);
        }
    #pragma unroll
    for (int r = 0; r < 4; ++r) {
        const int node = node0 + w * 16 + gq * 4 + r;
        if (node >= NN) continue;
        const float mean = s[r] * (1.0f / HID);
        const float var  = q[r] * (1.0f / HID) - mean * mean;
        const float rstd = rsqrtf(var + LN_EPS);
        #pragma unroll
        for (int c = 0; c < 8; ++c) {
            const float y = (acc[c][r] - mean) * rstd * gam[c] + bet[c];
            if (write_f32) {
                hout[(size_t)node * 128 + c * 16 + li] = y;
            } else {
                hb[(size_t)node * 128 + c * 16 + li] = (ushort)f2bf(y);
                h8[(size_t)node * 128 + c * 16 + li] = f2fp8(y);
            }
        }
    }
}

extern "C" void kernel_launch(void* const* d_in, const int* in_sizes, int n_in,
                              void* d_out, int out_size, void* d_ws, size_t ws_size,
                              hipStream_t stream) {
    const float* node_feat = (const float*)d_in[0];
    const float* topo      = (const float*)d_in[1];
    const float* embed     = (const float*)d_in[2];
    const float* W_in      = (const float*)d_in[3];
    const float* b_in      = (const float*)d_in[4];
    const float* ln0_g     = (const float*)d_in[5];
    const float* ln0_b     = (const float*)d_in[6];
    const float* Wl        = (const float*)d_in[7];
    const float* bl        = (const float*)d_in[8];
    const float* Wr        = (const float*)d_in[9];
    const float* ln_g      = (const float*)d_in[10];
    const float* ln_b      = (const float*)d_in[11];
    const int*   opcode    = (const int*)d_in[12];
    const int*   edge      = (const int*)d_in[13];
    const int*   e_src = edge;
    const int*   e_tgt = edge + NE;

    float* h = (float*)d_out;   // final output 100000 x 128 f32

    char* w = (char*)d_ws;
    ushort* hb     = (ushort*)w;  w += (size_t)NN * HID * sizeof(ushort);   // 25.6 MB
    ushort* aggb   = (ushort*)w;  w += (size_t)NN * HID * sizeof(ushort);   // 25.6 MB
    float* inv_deg = (float*)w;   w += 400016;
    int*   offs    = (int*)w;     w += 400016;    // NN+1 ints
    int*   bhist   = (int*)w;     w += 1024;
    int*   bpos    = (int*)w;     w += 1024;
    int*   bcur    = (int*)w;     w += 1024;
    int*   csr     = (int*)w;     w += (size_t)NE * sizeof(int);            // 6.4 MB
    // pairs (NE*8 = 12.8 MB) and h8 (NN*128 = 12.8 MB) ALIAS: pairs is consumed
    // by bucket_fill before input_proj writes h8 (same stream, sequential).
    uint2* pairs   = (uint2*)w;
    uchar* h8      = (uchar*)w;   w += (size_t)NE * sizeof(uint2);          // 12.8 MB
    ushort* winp   = (ushort*)w;  w += 7 * 8 * 64 * 8 * sizeof(ushort);     // 57 KB
    ushort* wcat   = (ushort*)w;  w += 4 * 8 * 8 * 64 * 8 * sizeof(ushort); // 262 KB

    pack_weights_kernel<<<78, 256, 0, stream>>>(W_in, Wl, Wr, winp, wcat);

    // CSR build first (pairs buffer), then input_proj overwrites pairs as h8
    hipMemsetAsync(bhist, 0, NBUCK * sizeof(int), stream);
    hist_kernel<<<(NE + 8191) / 8192, 256, 0, stream>>>(e_tgt, bhist);
    bucket_scan_kernel<<<1, 256, 0, stream>>>(bhist, bpos, bcur);
    partition_kernel<<<(NE + 2047) / 2048, 256, 0, stream>>>(e_src, e_tgt, bcur, pairs);
    bucket_fill_kernel<<<NBUCK, 256, 0, stream>>>(pairs, bpos, bhist, offs, inv_deg, csr);

    input_proj_mfma<<<(NN + 31) / 32, 128, 0, stream>>>(
        node_feat, topo, embed, opcode, winp, b_in, ln0_g, ln0_b, hb, h8);

    for (int layer = 0; layer < 4; ++layer) {
        gather_kernel<<<8 * 3136, 256, 0, stream>>>(h8, csr, offs, inv_deg, aggb);
        layer_mfma<<<(NN + 63) / 64, 256, 0, stream>>>(
            hb, h8, aggb, wcat + (size_t)layer * 8 * 8 * 64 * 8,
            bl + (size_t)layer * HID,
            ln_g + (size_t)layer * HID, ln_b + (size_t)layer * HID,
            h, layer == 3 ? 1 : 0);
    }
}